// Round 1
// baseline (679.983 us; speedup 1.0000x reference)
//
#include <hip/hip_runtime.h>
#include <stdint.h>

#define NEG_SLOPE 0.2f
#define EPSV 1e-16f

typedef __attribute__((ext_vector_type(8))) short short8;
typedef __attribute__((ext_vector_type(4))) float f32x4;

// round-to-nearest-even fp32 -> bf16 bits
__device__ inline short bf16r(float f){
  union { float f; unsigned u; } v; v.f = f;
  unsigned r = (v.u + 0x7FFFu + ((v.u >> 16) & 1u)) >> 16;
  return (short)r;
}

// ---------------- edge access (int32 or int64 edge_index, [2,E] row-major) ----------------
__device__ inline void get_edge(const void* ei, int is64, int E, int e, int& s, int& d){
  if (e >= E){ s = d = e - E; return; }  // self loops appended
  if (is64){
    const long long* p = (const long long*)ei;
    s = (int)p[e]; d = (int)p[(long long)E + e];
  } else {
    const int* p = (const int*)ei;
    s = p[e]; d = p[E + e];
  }
}

__global__ void detect_dtype(const int* ei32, int* flag){
  if (threadIdx.x == 0 && blockIdx.x == 0){
    int nz = 0;
    for (int i = 0; i < 64; ++i) nz |= ei32[2*i + 1];  // int64: high words all 0
    *flag = (nz == 0) ? 1 : 0;
  }
}

// ---------------- fp32 -> bf16 conversion ----------------
__global__ void cvt_to_bf16(const float* __restrict__ x, short* __restrict__ xb, int n){
  int i = blockIdx.x*blockDim.x + threadIdx.x;
  if (i < n) xb[i] = bf16r(x[i]);
}

// ---------------- pack W [K x NCOL] row-major fp32 -> per-fragment bf16 layout ----------------
// Wp[(((kt*NNT+nt)*4+q)*16 + n16)*8 + j] = bf16(W[(kt*32+q*8+j)][nt*16+n16])
__global__ void pack_w(const float* __restrict__ W, short* __restrict__ Wp, int K, int NCOL){
  int NNT = NCOL >> 4;
  int total = K*NCOL;
  int idx = blockIdx.x*blockDim.x + threadIdx.x;
  if (idx >= total) return;
  int j = idx & 7, n16 = (idx >> 3) & 15, q = (idx >> 7) & 3, tile = idx >> 9;
  int nt = tile % NNT, kt = tile / NNT;
  int k = kt*32 + q*8 + j, n = nt*16 + n16;
  Wp[idx] = bf16r(W[k*NCOL + n]);
}

// ---------------- MFMA GEMM: C[M x NCOL] = A[M x K](bf16) * W(bf16 packed), fp32 out ----------------
template<int K, int NCOL>
__global__ __launch_bounds__(256) void gemm_mfma(const short* __restrict__ A, const short* __restrict__ Bp,
                                                 float* __restrict__ C, int M){
  constexpr int NKT = K/32, NNT = NCOL/16;
  int wave = (blockIdx.x*256 + (int)threadIdx.x) >> 6;
  int lane = threadIdx.x & 63;
  int row0 = wave << 4;
  if (row0 >= M) return;
  int m = lane & 15, q = lane >> 4;
  f32x4 acc[NNT];
#pragma unroll
  for (int i = 0; i < NNT; ++i) acc[i] = (f32x4){0.f,0.f,0.f,0.f};
#pragma unroll
  for (int kt = 0; kt < NKT; ++kt){
    short8 a = *(const short8*)(A + (size_t)(row0 + m)*K + kt*32 + q*8);
#pragma unroll
    for (int nt = 0; nt < NNT; ++nt){
      short8 b = *(const short8*)(Bp + (size_t)(((kt*NNT + nt)*4 + q)*16 + m)*8);
      acc[nt] = __builtin_amdgcn_mfma_f32_16x16x32_bf16(a, b, acc[nt], 0, 0, 0);
    }
  }
#pragma unroll
  for (int nt = 0; nt < NNT; ++nt){
#pragma unroll
    for (int r = 0; r < 4; ++r){
      C[(size_t)(row0 + q*4 + r)*NCOL + nt*16 + m] = acc[nt][r];
    }
  }
}

// ---------------- attention logit reductions ----------------
__global__ void logits_l1(const float* __restrict__ h1, const float* __restrict__ att_s,
                          const float* __restrict__ att_d, float* __restrict__ asrc,
                          float* __restrict__ adst, int N){
  int tid = threadIdx.x;
  int n = blockIdx.x*4 + (tid >> 6);
  int j = tid & 63;
  if (n >= N) return;
  float h = h1[(size_t)n*64 + j];
  float ps = h * att_s[j];
  float pd = h * att_d[j];
#pragma unroll
  for (int mm = 4; mm; mm >>= 1){ ps += __shfl_xor(ps, mm, 8); pd += __shfl_xor(pd, mm, 8); }
  if ((j & 7) == 0){ asrc[n*8 + (j >> 3)] = ps; adst[n*8 + (j >> 3)] = pd; }
}

__global__ void logits_l2(const float* __restrict__ h2, const float* __restrict__ att_s,
                          const float* __restrict__ att_d, float* __restrict__ asrc,
                          float* __restrict__ adst, int N){
  int tid = threadIdx.x;
  int n = blockIdx.x*4 + (tid >> 6);
  int l = tid & 63;
  if (n >= N) return;
  float a = h2[(size_t)n*128 + l], b = h2[(size_t)n*128 + 64 + l];
  float ps = a*att_s[l] + b*att_s[64 + l];
  float pd = a*att_d[l] + b*att_d[64 + l];
#pragma unroll
  for (int mm = 32; mm; mm >>= 1){ ps += __shfl_xor(ps, mm, 64); pd += __shfl_xor(pd, mm, 64); }
  if (l == 0){ asrc[n] = ps; adst[n] = pd; }
}

// ---------------- CSR build: histogram, 3-kernel scan, scatter ----------------
__global__ void edge_hist(const void* ei, const int* flag, int E, int E2, int* counts){
  int is64 = *flag;
  for (int e = blockIdx.x*blockDim.x + threadIdx.x; e < E2; e += gridDim.x*blockDim.x){
    int s, d; get_edge(ei, is64, E, e, s, d);
    atomicAdd(&counts[d], 1);
  }
}

__global__ void scan_blocksum(const int* __restrict__ counts, int N, int* __restrict__ bsum){
  __shared__ int sd[256];
  int t = threadIdx.x;
  int i = blockIdx.x*256 + t;
  sd[t] = (i < N) ? counts[i] : 0;
  __syncthreads();
  for (int s = 128; s > 0; s >>= 1){
    if (t < s) sd[t] += sd[t + s];
    __syncthreads();
  }
  if (t == 0) bsum[blockIdx.x] = sd[0];
}

__global__ void scan_top(int* bsum, int nb){
  __shared__ int sd[256];
  int t = threadIdx.x;
  int orig = (t < nb) ? bsum[t] : 0;
  sd[t] = orig;
  __syncthreads();
  for (int off = 1; off < 256; off <<= 1){
    int v = (t >= off) ? sd[t - off] : 0;
    __syncthreads();
    sd[t] += v;
    __syncthreads();
  }
  if (t < nb) bsum[t] = sd[t] - orig;  // exclusive
}

__global__ void scan_final(const int* __restrict__ counts, int N, const int* __restrict__ bsum,
                           int* __restrict__ offs, int* __restrict__ cursor, int E2){
  __shared__ int sd[256];
  int t = threadIdx.x;
  int i = blockIdx.x*256 + t;
  int v = (i < N) ? counts[i] : 0;
  sd[t] = v;
  __syncthreads();
  for (int off = 1; off < 256; off <<= 1){
    int u = (t >= off) ? sd[t - off] : 0;
    __syncthreads();
    sd[t] += u;
    __syncthreads();
  }
  if (i < N){
    int ex = bsum[blockIdx.x] + sd[t] - v;
    offs[i] = ex; cursor[i] = ex;
  }
  if (i == 0) offs[N] = E2;
}

__global__ void edge_scatter(const void* ei, const int* flag, int E, int E2,
                             int* cursor, int* __restrict__ srcs){
  int is64 = *flag;
  for (int e = blockIdx.x*blockDim.x + threadIdx.x; e < E2; e += gridDim.x*blockDim.x){
    int s, d; get_edge(ei, is64, E, e, s, d);
    int pos = atomicAdd(&cursor[d], 1);
    srcs[pos] = s;
  }
}

// ---------------- node-parallel softmax-aggregation ----------------
// out_i = (sum_j e_ij * h_j) / (sum_j e_ij + eps); e_ij = exp(lrelu(asrc[j]+adst[i]))
// (valid: softmax invariant under constant shift; logits are O(1), no overflow)
__global__ void agg_l1(const float* __restrict__ h1, const float* __restrict__ asrc,
                       const float* __restrict__ adst, const int* __restrict__ offs,
                       const int* __restrict__ srcs, const float* __restrict__ bias,
                       short* __restrict__ hout, int N){
  int tid = threadIdx.x;
  int i = blockIdx.x*4 + (tid >> 6);
  int lane = tid & 63;
  if (i >= N) return;
  int hgrp = lane >> 3;
  float ad = adst[i*8 + hgrp];
  int beg = offs[i], end = offs[i + 1];
  float acc = 0.f, den = 0.f;
  for (int p = beg; p < end; ++p){
    int s = srcs[p];
    float z = asrc[s*8 + hgrp] + ad;
    z = (z >= 0.f) ? z : NEG_SLOPE*z;
    float e = __expf(z);
    den += e;
    acc = fmaf(e, h1[(size_t)s*64 + lane], acc);
  }
  float o = acc/(den + EPSV) + bias[lane];
  o = (o > 0.f) ? o : (__expf(o) - 1.f);   // ELU fused (feeds layer-2 GEMM as bf16)
  hout[(size_t)i*64 + lane] = bf16r(o);
}

__global__ void agg_l2(const float* __restrict__ h2, const float* __restrict__ asrc,
                       const float* __restrict__ adst, const int* __restrict__ offs,
                       const int* __restrict__ srcs, const float* __restrict__ bias,
                       float* __restrict__ out, int N){
  int tid = threadIdx.x;
  int i = blockIdx.x*4 + (tid >> 6);
  int lane = tid & 63;
  if (i >= N) return;
  float ad = adst[i];
  int beg = offs[i], end = offs[i + 1];
  float a0 = 0.f, a1 = 0.f, den = 0.f;
  for (int p = beg; p < end; ++p){
    int s = srcs[p];
    float z = asrc[s] + ad;
    z = (z >= 0.f) ? z : NEG_SLOPE*z;
    float e = __expf(z);
    den += e;
    a0 = fmaf(e, h2[(size_t)s*128 + lane], a0);
    a1 = fmaf(e, h2[(size_t)s*128 + 64 + lane], a1);
  }
  float inv = 1.f/(den + EPSV);
  out[(size_t)i*128 + lane]      = a0*inv + bias[lane];
  out[(size_t)i*128 + 64 + lane] = a1*inv + bias[64 + lane];
}

// ---------------- launch ----------------
extern "C" void kernel_launch(void* const* d_in, const int* in_sizes, int n_in,
                              void* d_out, int out_size, void* d_ws, size_t ws_size,
                              hipStream_t stream){
  const float* x   = (const float*)d_in[0];
  const void*  ei  = d_in[1];
  const float* W1  = (const float*)d_in[2];
  const float* as1 = (const float*)d_in[3];
  const float* ad1 = (const float*)d_in[4];
  const float* b1  = (const float*)d_in[5];
  const float* W2  = (const float*)d_in[6];
  const float* as2 = (const float*)d_in[7];
  const float* ad2 = (const float*)d_in[8];
  const float* b2  = (const float*)d_in[9];

  int N  = in_sizes[0] / 128;
  int E  = in_sizes[1] / 2;
  int E2 = E + N;

  char* p = (char*)d_ws;
  auto alloc = [&](size_t bytes) -> void* {
    void* r = (void*)p;
    p += (bytes + 255) & ~(size_t)255;
    return r;
  };
  short* xb    = (short*)alloc((size_t)N*128*2);
  short* W1p   = (short*)alloc((size_t)128*64*2);
  short* W2p   = (short*)alloc((size_t)64*128*2);
  float* h1    = (float*)alloc((size_t)N*64*4);
  float* asrc1 = (float*)alloc((size_t)N*8*4);
  float* adst1 = (float*)alloc((size_t)N*8*4);
  short* hin2  = (short*)alloc((size_t)N*64*2);
  float* h2    = (float*)alloc((size_t)N*128*4);
  float* asrc2 = (float*)alloc((size_t)N*4);
  float* adst2 = (float*)alloc((size_t)N*4);
  int*   counts= (int*)alloc((size_t)N*4);
  int*   offs  = (int*)alloc((size_t)(N + 1)*4);
  int*   cursor= (int*)alloc((size_t)N*4);
  int*   bsum  = (int*)alloc(1024);
  int*   srcs  = (int*)alloc((size_t)E2*4);
  int*   flag  = (int*)alloc(4);

  dim3 B(256);
  detect_dtype<<<1, 64, 0, stream>>>((const int*)ei, flag);

  int ntot = N*128;
  cvt_to_bf16<<<(ntot + 255)/256, B, 0, stream>>>(x, xb, ntot);
  pack_w<<<(128*64 + 255)/256, B, 0, stream>>>(W1, W1p, 128, 64);
  pack_w<<<(64*128 + 255)/256, B, 0, stream>>>(W2, W2p, 64, 128);

  int nwav = (N + 15)/16;
  gemm_mfma<128,64><<<(nwav + 3)/4, B, 0, stream>>>(xb, W1p, h1, N);
  logits_l1<<<(N + 3)/4, B, 0, stream>>>(h1, as1, ad1, asrc1, adst1, N);

  // CSR by dst (reused by both layers)
  hipMemsetAsync(counts, 0, (size_t)N*4, stream);
  edge_hist<<<2048, B, 0, stream>>>(ei, flag, E, E2, counts);
  int nb = (N + 255)/256;
  scan_blocksum<<<nb, B, 0, stream>>>(counts, N, bsum);
  scan_top<<<1, B, 0, stream>>>(bsum, nb);
  scan_final<<<nb, B, 0, stream>>>(counts, N, bsum, offs, cursor, E2);
  edge_scatter<<<2048, B, 0, stream>>>(ei, flag, E, E2, cursor, srcs);

  agg_l1<<<(N + 3)/4, B, 0, stream>>>(h1, asrc1, adst1, offs, srcs, b1, hin2, N);

  gemm_mfma<64,128><<<(nwav + 3)/4, B, 0, stream>>>(hin2, W2p, h2, N);
  logits_l2<<<(N + 3)/4, B, 0, stream>>>(h2, as2, ad2, asrc2, adst2, N);
  agg_l2<<<(N + 3)/4, B, 0, stream>>>(h2, asrc2, adst2, offs, srcs, b2, (float*)d_out, N);
}

// Round 2
// 511.338 us; speedup vs baseline: 1.3298x; 1.3298x over previous
//
#include <hip/hip_runtime.h>
#include <stdint.h>

#define NEG_SLOPE 0.2f
#define EPSV 1e-16f

typedef __attribute__((ext_vector_type(8))) short short8;
typedef __attribute__((ext_vector_type(4))) float f32x4;

// round-to-nearest-even fp32 -> bf16 bits
__device__ inline short bf16r(float f){
  union { float f; unsigned u; } v; v.f = f;
  unsigned r = (v.u + 0x7FFFu + ((v.u >> 16) & 1u)) >> 16;
  return (short)r;
}

// ---------------- edge access (int32 or int64 edge_index, [2,E] row-major) ----------------
__device__ inline void get_edge(const void* ei, int is64, int E, int e, int& s, int& d){
  if (e >= E){ s = d = e - E; return; }  // self loops appended
  if (is64){
    const long long* p = (const long long*)ei;
    s = (int)p[e]; d = (int)p[(long long)E + e];
  } else {
    const int* p = (const int*)ei;
    s = p[e]; d = p[E + e];
  }
}

__global__ void detect_dtype(const int* ei32, int* flag){
  if (threadIdx.x == 0 && blockIdx.x == 0){
    int nz = 0;
    for (int i = 0; i < 64; ++i) nz |= ei32[2*i + 1];  // int64: high words all 0
    *flag = (nz == 0) ? 1 : 0;
  }
}

// ---------------- fp32 -> bf16 conversion (vectorized: 4 elems/thread) ----------------
__global__ void cvt_to_bf16(const float* __restrict__ x, short* __restrict__ xb, int n4){
  int i = blockIdx.x*blockDim.x + threadIdx.x;
  if (i >= n4) return;
  f32x4 v = *(const f32x4*)(x + (size_t)i*4);
  short4 o;
  o.x = bf16r(v[0]); o.y = bf16r(v[1]); o.z = bf16r(v[2]); o.w = bf16r(v[3]);
  *(short4*)(xb + (size_t)i*4) = o;
}

// ---------------- pack W [K x NCOL] row-major fp32 -> per-fragment bf16 layout ----------------
__global__ void pack_w(const float* __restrict__ W, short* __restrict__ Wp, int K, int NCOL){
  int NNT = NCOL >> 4;
  int total = K*NCOL;
  int idx = blockIdx.x*blockDim.x + threadIdx.x;
  if (idx >= total) return;
  int j = idx & 7, n16 = (idx >> 3) & 15, q = (idx >> 7) & 3, tile = idx >> 9;
  int nt = tile % NNT, kt = tile / NNT;
  int k = kt*32 + q*8 + j, n = nt*16 + n16;
  Wp[idx] = bf16r(W[k*NCOL + n]);
}

// ---------------- MFMA GEMM: C[M x NCOL] = A[M x K](bf16) * W(bf16 packed), fp32 out ----------------
template<int K, int NCOL>
__global__ __launch_bounds__(256) void gemm_mfma(const short* __restrict__ A, const short* __restrict__ Bp,
                                                 float* __restrict__ C, int M){
  constexpr int NKT = K/32, NNT = NCOL/16;
  int wave = (blockIdx.x*256 + (int)threadIdx.x) >> 6;
  int lane = threadIdx.x & 63;
  int row0 = wave << 4;
  if (row0 >= M) return;
  int m = lane & 15, q = lane >> 4;
  f32x4 acc[NNT];
#pragma unroll
  for (int i = 0; i < NNT; ++i) acc[i] = (f32x4){0.f,0.f,0.f,0.f};
#pragma unroll
  for (int kt = 0; kt < NKT; ++kt){
    short8 a = *(const short8*)(A + (size_t)(row0 + m)*K + kt*32 + q*8);
#pragma unroll
    for (int nt = 0; nt < NNT; ++nt){
      short8 b = *(const short8*)(Bp + (size_t)(((kt*NNT + nt)*4 + q)*16 + m)*8);
      acc[nt] = __builtin_amdgcn_mfma_f32_16x16x32_bf16(a, b, acc[nt], 0, 0, 0);
    }
  }
#pragma unroll
  for (int nt = 0; nt < NNT; ++nt){
#pragma unroll
    for (int r = 0; r < 4; ++r){
      C[(size_t)(row0 + q*4 + r)*NCOL + nt*16 + m] = acc[nt][r];
    }
  }
}

// ---------------- attention logit reductions ----------------
__global__ void logits_l1(const float* __restrict__ h1, const float* __restrict__ att_s,
                          const float* __restrict__ att_d, float* __restrict__ asrc,
                          float* __restrict__ adst, int N){
  int tid = threadIdx.x;
  int n = blockIdx.x*4 + (tid >> 6);
  int j = tid & 63;
  if (n >= N) return;
  float h = h1[(size_t)n*64 + j];
  float ps = h * att_s[j];
  float pd = h * att_d[j];
#pragma unroll
  for (int mm = 4; mm; mm >>= 1){ ps += __shfl_xor(ps, mm, 8); pd += __shfl_xor(pd, mm, 8); }
  if ((j & 7) == 0){ asrc[n*8 + (j >> 3)] = ps; adst[n*8 + (j >> 3)] = pd; }
}

__global__ void logits_l2(const float* __restrict__ h2, const float* __restrict__ att_s,
                          const float* __restrict__ att_d, float* __restrict__ asrc,
                          float* __restrict__ adst, int N){
  int tid = threadIdx.x;
  int n = blockIdx.x*4 + (tid >> 6);
  int l = tid & 63;
  if (n >= N) return;
  float a = h2[(size_t)n*128 + l], b = h2[(size_t)n*128 + 64 + l];
  float ps = a*att_s[l] + b*att_s[64 + l];
  float pd = a*att_d[l] + b*att_d[64 + l];
#pragma unroll
  for (int mm = 32; mm; mm >>= 1){ ps += __shfl_xor(ps, mm, 64); pd += __shfl_xor(pd, mm, 64); }
  if (l == 0){ asrc[n] = ps; adst[n] = pd; }
}

// ---------------- CSR build: histogram, 3-kernel scan, scatter ----------------
__global__ void edge_hist(const void* ei, const int* flag, int E, int E2, int* counts){
  int is64 = *flag;
  for (int e = blockIdx.x*blockDim.x + threadIdx.x; e < E2; e += gridDim.x*blockDim.x){
    int s, d; get_edge(ei, is64, E, e, s, d);
    atomicAdd(&counts[d], 1);
  }
}

__global__ void scan_blocksum(const int* __restrict__ counts, int N, int* __restrict__ bsum){
  __shared__ int sd[256];
  int t = threadIdx.x;
  int i = blockIdx.x*256 + t;
  sd[t] = (i < N) ? counts[i] : 0;
  __syncthreads();
  for (int s = 128; s > 0; s >>= 1){
    if (t < s) sd[t] += sd[t + s];
    __syncthreads();
  }
  if (t == 0) bsum[blockIdx.x] = sd[0];
}

__global__ void scan_top(int* bsum, int nb){
  __shared__ int sd[256];
  int t = threadIdx.x;
  int orig = (t < nb) ? bsum[t] : 0;
  sd[t] = orig;
  __syncthreads();
  for (int off = 1; off < 256; off <<= 1){
    int v = (t >= off) ? sd[t - off] : 0;
    __syncthreads();
    sd[t] += v;
    __syncthreads();
  }
  if (t < nb) bsum[t] = sd[t] - orig;  // exclusive
}

__global__ void scan_final(const int* __restrict__ counts, int N, const int* __restrict__ bsum,
                           int* __restrict__ offs, int* __restrict__ cursor, int E2){
  __shared__ int sd[256];
  int t = threadIdx.x;
  int i = blockIdx.x*256 + t;
  int v = (i < N) ? counts[i] : 0;
  sd[t] = v;
  __syncthreads();
  for (int off = 1; off < 256; off <<= 1){
    int u = (t >= off) ? sd[t - off] : 0;
    __syncthreads();
    sd[t] += u;
    __syncthreads();
  }
  if (i < N){
    int ex = bsum[blockIdx.x] + sd[t] - v;
    offs[i] = ex; cursor[i] = ex;
  }
  if (i == 0) offs[N] = E2;
}

__global__ void edge_scatter(const void* ei, const int* flag, int E, int E2,
                             int* cursor, int* __restrict__ srcs){
  int is64 = *flag;
  for (int e = blockIdx.x*blockDim.x + threadIdx.x; e < E2; e += gridDim.x*blockDim.x){
    int s, d; get_edge(ei, is64, E, e, s, d);
    int pos = atomicAdd(&cursor[d], 1);
    srcs[pos] = s;
  }
}

// ---------------- node-parallel softmax-aggregation (software-pipelined, unroll 8) ----------------
// out_i = (sum_j e_ij * h_j) / (sum_j e_ij + eps); e_ij = exp(lrelu(asrc[j]+adst[i]))
__global__ __launch_bounds__(256) void agg_l1(const float* __restrict__ h1, const float* __restrict__ asrc,
                       const float* __restrict__ adst, const int* __restrict__ offs,
                       const int* __restrict__ srcs, const float* __restrict__ bias,
                       short* __restrict__ hout, int N){
  int tid = threadIdx.x;
  int i = blockIdx.x*4 + (tid >> 6);
  int lane = tid & 63;
  if (i >= N) return;
  int hgrp = lane >> 3;
  float ad = adst[i*8 + hgrp];
  int beg = offs[i], end = offs[i + 1];
  float acc = 0.f, den = 0.f;
  int p = beg;
  for (; p + 8 <= end; p += 8){
    int s[8];
#pragma unroll
    for (int u = 0; u < 8; ++u) s[u] = srcs[p + u];
    float az[8];
#pragma unroll
    for (int u = 0; u < 8; ++u) az[u] = asrc[s[u]*8 + hgrp];
    float v[8];
#pragma unroll
    for (int u = 0; u < 8; ++u) v[u] = h1[(size_t)s[u]*64 + lane];
#pragma unroll
    for (int u = 0; u < 8; ++u){
      float z = az[u] + ad;
      z = (z >= 0.f) ? z : NEG_SLOPE*z;
      float e = __expf(z);
      den += e;
      acc = fmaf(e, v[u], acc);
    }
  }
  for (; p < end; ++p){
    int s = srcs[p];
    float z = asrc[s*8 + hgrp] + ad;
    z = (z >= 0.f) ? z : NEG_SLOPE*z;
    float e = __expf(z);
    den += e;
    acc = fmaf(e, h1[(size_t)s*64 + lane], acc);
  }
  float o = acc/(den + EPSV) + bias[lane];
  o = (o > 0.f) ? o : (__expf(o) - 1.f);   // ELU fused (feeds layer-2 GEMM as bf16)
  hout[(size_t)i*64 + lane] = bf16r(o);
}

__global__ __launch_bounds__(256) void agg_l2(const float* __restrict__ h2, const float* __restrict__ asrc,
                       const float* __restrict__ adst, const int* __restrict__ offs,
                       const int* __restrict__ srcs, const float* __restrict__ bias,
                       float* __restrict__ out, int N){
  int tid = threadIdx.x;
  int i = blockIdx.x*4 + (tid >> 6);
  int lane = tid & 63;
  if (i >= N) return;
  float ad = adst[i];
  int beg = offs[i], end = offs[i + 1];
  float a0 = 0.f, a1 = 0.f, den = 0.f;
  int p = beg;
  for (; p + 8 <= end; p += 8){
    int s[8];
#pragma unroll
    for (int u = 0; u < 8; ++u) s[u] = srcs[p + u];
    float az[8];
#pragma unroll
    for (int u = 0; u < 8; ++u) az[u] = asrc[s[u]];
    float v0[8], v1[8];
#pragma unroll
    for (int u = 0; u < 8; ++u){
      v0[u] = h2[(size_t)s[u]*128 + lane];
      v1[u] = h2[(size_t)s[u]*128 + 64 + lane];
    }
#pragma unroll
    for (int u = 0; u < 8; ++u){
      float z = az[u] + ad;
      z = (z >= 0.f) ? z : NEG_SLOPE*z;
      float e = __expf(z);
      den += e;
      a0 = fmaf(e, v0[u], a0);
      a1 = fmaf(e, v1[u], a1);
    }
  }
  for (; p < end; ++p){
    int s = srcs[p];
    float z = asrc[s] + ad;
    z = (z >= 0.f) ? z : NEG_SLOPE*z;
    float e = __expf(z);
    den += e;
    a0 = fmaf(e, h2[(size_t)s*128 + lane], a0);
    a1 = fmaf(e, h2[(size_t)s*128 + 64 + lane], a1);
  }
  float inv = 1.f/(den + EPSV);
  out[(size_t)i*128 + lane]      = a0*inv + bias[lane];
  out[(size_t)i*128 + 64 + lane] = a1*inv + bias[64 + lane];
}

// ---------------- launch ----------------
extern "C" void kernel_launch(void* const* d_in, const int* in_sizes, int n_in,
                              void* d_out, int out_size, void* d_ws, size_t ws_size,
                              hipStream_t stream){
  const float* x   = (const float*)d_in[0];
  const void*  ei  = d_in[1];
  const float* W1  = (const float*)d_in[2];
  const float* as1 = (const float*)d_in[3];
  const float* ad1 = (const float*)d_in[4];
  const float* b1  = (const float*)d_in[5];
  const float* W2  = (const float*)d_in[6];
  const float* as2 = (const float*)d_in[7];
  const float* ad2 = (const float*)d_in[8];
  const float* b2  = (const float*)d_in[9];

  int N  = in_sizes[0] / 128;
  int E  = in_sizes[1] / 2;
  int E2 = E + N;

  char* p = (char*)d_ws;
  auto alloc = [&](size_t bytes) -> void* {
    void* r = (void*)p;
    p += (bytes + 255) & ~(size_t)255;
    return r;
  };
  short* xb    = (short*)alloc((size_t)N*128*2);
  short* W1p   = (short*)alloc((size_t)128*64*2);
  short* W2p   = (short*)alloc((size_t)64*128*2);
  float* h1    = (float*)alloc((size_t)N*64*4);
  float* asrc1 = (float*)alloc((size_t)N*8*4);
  float* adst1 = (float*)alloc((size_t)N*8*4);
  short* hin2  = (short*)alloc((size_t)N*64*2);
  float* h2    = (float*)alloc((size_t)N*128*4);
  float* asrc2 = (float*)alloc((size_t)N*4);
  float* adst2 = (float*)alloc((size_t)N*4);
  int*   counts= (int*)alloc((size_t)N*4);
  int*   offs  = (int*)alloc((size_t)(N + 1)*4);
  int*   cursor= (int*)alloc((size_t)N*4);
  int*   bsum  = (int*)alloc(1024);
  int*   srcs  = (int*)alloc((size_t)E2*4);
  int*   flag  = (int*)alloc(4);

  dim3 B(256);
  detect_dtype<<<1, 64, 0, stream>>>((const int*)ei, flag);

  int n4 = N*128/4;
  cvt_to_bf16<<<(n4 + 255)/256, B, 0, stream>>>(x, xb, n4);
  pack_w<<<(128*64 + 255)/256, B, 0, stream>>>(W1, W1p, 128, 64);
  pack_w<<<(64*128 + 255)/256, B, 0, stream>>>(W2, W2p, 64, 128);

  int nwav = (N + 15)/16;
  gemm_mfma<128,64><<<(nwav + 3)/4, B, 0, stream>>>(xb, W1p, h1, N);
  logits_l1<<<(N + 3)/4, B, 0, stream>>>(h1, as1, ad1, asrc1, adst1, N);

  // CSR by dst (reused by both layers)
  hipMemsetAsync(counts, 0, (size_t)N*4, stream);
  edge_hist<<<2048, B, 0, stream>>>(ei, flag, E, E2, counts);
  int nb = (N + 255)/256;
  scan_blocksum<<<nb, B, 0, stream>>>(counts, N, bsum);
  scan_top<<<1, B, 0, stream>>>(bsum, nb);
  scan_final<<<nb, B, 0, stream>>>(counts, N, bsum, offs, cursor, E2);
  edge_scatter<<<2048, B, 0, stream>>>(ei, flag, E, E2, cursor, srcs);

  agg_l1<<<(N + 3)/4, B, 0, stream>>>(h1, asrc1, adst1, offs, srcs, b1, hin2, N);

  gemm_mfma<64,128><<<(nwav + 3)/4, B, 0, stream>>>(hin2, W2p, h2, N);
  logits_l2<<<(N + 3)/4, B, 0, stream>>>(h2, as2, ad2, asrc2, adst2, N);
  agg_l2<<<(N + 3)/4, B, 0, stream>>>(h2, asrc2, adst2, offs, srcs, b2, (float*)d_out, N);
}

// Round 3
// 364.178 us; speedup vs baseline: 1.8672x; 1.4041x over previous
//
#include <hip/hip_runtime.h>
#include <stdint.h>

#define NEG_SLOPE 0.2f
#define EPSV 1e-16f
#define NBLK 256   // scatter/histogram blocks (fixed, deterministic edge ranges)

typedef __attribute__((ext_vector_type(8))) short short8;
typedef __attribute__((ext_vector_type(4))) float f32x4;

// round-to-nearest-even fp32 -> bf16 bits
__device__ inline short bf16r(float f){
  union { float f; unsigned u; } v; v.f = f;
  unsigned r = (v.u + 0x7FFFu + ((v.u >> 16) & 1u)) >> 16;
  return (short)r;
}

// ---------------- edge access (int32 or int64 edge_index, [2,E] row-major) ----------------
__device__ inline void get_edge(const void* ei, int is64, int E, int e, int& s, int& d){
  if (e >= E){ s = d = e - E; return; }  // self loops appended
  if (is64){
    const long long* p = (const long long*)ei;
    s = (int)p[e]; d = (int)p[(long long)E + e];
  } else {
    const int* p = (const int*)ei;
    s = p[e]; d = p[E + e];
  }
}

__device__ inline int get_dst(const void* ei, int is64, int E, int e){
  if (e >= E) return e - E;
  if (is64) return (int)((const long long*)ei)[(long long)E + e];
  return ((const int*)ei)[E + e];
}

__global__ void detect_dtype(const int* ei32, int* flag){
  if (threadIdx.x == 0 && blockIdx.x == 0){
    int nz = 0;
    for (int i = 0; i < 64; ++i) nz |= ei32[2*i + 1];  // int64: high words all 0
    *flag = (nz == 0) ? 1 : 0;
  }
}

// ---------------- fp32 -> bf16 conversion (vectorized: 4 elems/thread) ----------------
__global__ void cvt_to_bf16(const float* __restrict__ x, short* __restrict__ xb, int n4){
  int i = blockIdx.x*blockDim.x + threadIdx.x;
  if (i >= n4) return;
  f32x4 v = *(const f32x4*)(x + (size_t)i*4);
  short4 o;
  o.x = bf16r(v[0]); o.y = bf16r(v[1]); o.z = bf16r(v[2]); o.w = bf16r(v[3]);
  *(short4*)(xb + (size_t)i*4) = o;
}

// ---------------- pack W [K x NCOL] row-major fp32 -> per-fragment bf16 layout ----------------
__global__ void pack_w(const float* __restrict__ W, short* __restrict__ Wp, int K, int NCOL){
  int NNT = NCOL >> 4;
  int total = K*NCOL;
  int idx = blockIdx.x*blockDim.x + threadIdx.x;
  if (idx >= total) return;
  int j = idx & 7, n16 = (idx >> 3) & 15, q = (idx >> 7) & 3, tile = idx >> 9;
  int nt = tile % NNT, kt = tile / NNT;
  int k = kt*32 + q*8 + j, n = nt*16 + n16;
  Wp[idx] = bf16r(W[k*NCOL + n]);
}

// ---------------- MFMA GEMM: C[M x NCOL] = A[M x K](bf16) * W(bf16 packed), fp32 out ----------------
template<int K, int NCOL>
__global__ __launch_bounds__(256) void gemm_mfma(const short* __restrict__ A, const short* __restrict__ Bp,
                                                 float* __restrict__ C, int M){
  constexpr int NKT = K/32, NNT = NCOL/16;
  int wave = (blockIdx.x*256 + (int)threadIdx.x) >> 6;
  int lane = threadIdx.x & 63;
  int row0 = wave << 4;
  if (row0 >= M) return;
  int m = lane & 15, q = lane >> 4;
  f32x4 acc[NNT];
#pragma unroll
  for (int i = 0; i < NNT; ++i) acc[i] = (f32x4){0.f,0.f,0.f,0.f};
#pragma unroll
  for (int kt = 0; kt < NKT; ++kt){
    short8 a = *(const short8*)(A + (size_t)(row0 + m)*K + kt*32 + q*8);
#pragma unroll
    for (int nt = 0; nt < NNT; ++nt){
      short8 b = *(const short8*)(Bp + (size_t)(((kt*NNT + nt)*4 + q)*16 + m)*8);
      acc[nt] = __builtin_amdgcn_mfma_f32_16x16x32_bf16(a, b, acc[nt], 0, 0, 0);
    }
  }
#pragma unroll
  for (int nt = 0; nt < NNT; ++nt){
#pragma unroll
    for (int r = 0; r < 4; ++r){
      C[(size_t)(row0 + q*4 + r)*NCOL + nt*16 + m] = acc[nt][r];
    }
  }
}

// ---------------- attention logit reductions ----------------
__global__ void logits_l1(const float* __restrict__ h1, const float* __restrict__ att_s,
                          const float* __restrict__ att_d, float* __restrict__ asrc,
                          float* __restrict__ adst, int N){
  int tid = threadIdx.x;
  int n = blockIdx.x*4 + (tid >> 6);
  int j = tid & 63;
  if (n >= N) return;
  float h = h1[(size_t)n*64 + j];
  float ps = h * att_s[j];
  float pd = h * att_d[j];
#pragma unroll
  for (int mm = 4; mm; mm >>= 1){ ps += __shfl_xor(ps, mm, 8); pd += __shfl_xor(pd, mm, 8); }
  if ((j & 7) == 0){ asrc[n*8 + (j >> 3)] = ps; adst[n*8 + (j >> 3)] = pd; }
}

__global__ void logits_l2(const float* __restrict__ h2, const float* __restrict__ att_s,
                          const float* __restrict__ att_d, float* __restrict__ asrc,
                          float* __restrict__ adst, int N){
  int tid = threadIdx.x;
  int n = blockIdx.x*4 + (tid >> 6);
  int l = tid & 63;
  if (n >= N) return;
  float a = h2[(size_t)n*128 + l], b = h2[(size_t)n*128 + 64 + l];
  float ps = a*att_s[l] + b*att_s[64 + l];
  float pd = a*att_d[l] + b*att_d[64 + l];
#pragma unroll
  for (int mm = 32; mm; mm >>= 1){ ps += __shfl_xor(ps, mm, 64); pd += __shfl_xor(pd, mm, 64); }
  if (l == 0){ asrc[n] = ps; adst[n] = pd; }
}

// ================= CSR build: two-level counting sort (no global atomics) =================
// Buckets of 256 dst nodes each: bucket = d >> 8.  NB = ceil(N/256) <= 256 (N <= 65536).

// P1: per-block bucket histogram (LDS), write block_counts[blk][bucket]
__global__ __launch_bounds__(256) void p1_hist(const void* ei, const int* flag, int E, int E2,
                                               int* __restrict__ block_counts){
  __shared__ int h[256];
  int t = threadIdx.x, blk = blockIdx.x;
  h[t] = 0; __syncthreads();
  int chunk = (E2 + NBLK - 1)/NBLK;
  int beg = blk*chunk, end = min(beg + chunk, E2);
  int is64 = *flag;
  for (int e = beg + t; e < end; e += 256){
    int d = get_dst(ei, is64, E, e);
    atomicAdd(&h[d >> 8], 1);
  }
  __syncthreads();
  block_counts[blk*256 + t] = h[t];
}

// P2a: bucket totals + exclusive scan -> bucket_base[0..256]
__global__ void p2_bucket_scan(const int* __restrict__ block_counts, int* __restrict__ bucket_base){
  __shared__ int sd[256];
  int t = threadIdx.x;
  int tot = 0;
  for (int b = 0; b < NBLK; ++b) tot += block_counts[b*256 + t];
  sd[t] = tot; __syncthreads();
  for (int off = 1; off < 256; off <<= 1){
    int v = (t >= off) ? sd[t - off] : 0;
    __syncthreads(); sd[t] += v; __syncthreads();
  }
  bucket_base[t] = sd[t] - tot;            // exclusive
  if (t == 255) bucket_base[256] = sd[255];
}

// P2b: per-(block,bucket) start offset.  grid = 256 (one block per bucket)
__global__ void p2_block_off(const int* __restrict__ block_counts, const int* __restrict__ bucket_base,
                             int* __restrict__ block_off){
  __shared__ int sd[256];
  int b = blockIdx.x, t = threadIdx.x;
  int v = block_counts[t*256 + b];
  sd[t] = v; __syncthreads();
  for (int off = 1; off < 256; off <<= 1){
    int u = (t >= off) ? sd[t - off] : 0;
    __syncthreads(); sd[t] += u; __syncthreads();
  }
  block_off[t*256 + b] = bucket_base[b] + sd[t] - v;
}

// P3: scatter (s,d) pairs into bucket-major runs; LDS cursors only
__global__ __launch_bounds__(256) void p3_scatter(const void* ei, const int* flag, int E, int E2,
                                                  const int* __restrict__ block_off,
                                                  int2* __restrict__ pairs){
  __shared__ int cur[256];
  int t = threadIdx.x, blk = blockIdx.x;
  cur[t] = block_off[blk*256 + t];
  __syncthreads();
  int chunk = (E2 + NBLK - 1)/NBLK;
  int beg = blk*chunk, end = min(beg + chunk, E2);
  int is64 = *flag;
  for (int e = beg + t; e < end; e += 256){
    int s, d; get_edge(ei, is64, E, e, s, d);
    int pos = atomicAdd(&cur[d >> 8], 1);
    pairs[pos] = make_int2(s, d);
  }
}

// P4: in-bucket counting sort -> offs[], srcs[].  grid = NB (one block per bucket)
__global__ __launch_bounds__(256) void p4_sort(const int2* __restrict__ pairs,
                                               const int* __restrict__ bucket_base,
                                               int N, int E2,
                                               int* __restrict__ offs, int* __restrict__ srcs){
  __shared__ int hist[256];
  __shared__ int cur[256];
  int b = blockIdx.x, t = threadIdx.x;
  int base = bucket_base[b], cnt = bucket_base[b + 1] - base;
  hist[t] = 0; __syncthreads();
  for (int p = t; p < cnt; p += 256){
    int2 sd2 = pairs[base + p];
    atomicAdd(&hist[sd2.y & 255], 1);
  }
  __syncthreads();
  int v = hist[t];
  cur[t] = v; __syncthreads();
  for (int off = 1; off < 256; off <<= 1){
    int u = (t >= off) ? cur[t - off] : 0;
    __syncthreads(); cur[t] += u; __syncthreads();
  }
  int ex = cur[t] - v;   // exclusive prefix within bucket
  __syncthreads();
  cur[t] = ex;
  int node = b*256 + t;
  if (node < N) offs[node] = base + ex;
  __syncthreads();
  for (int p = t; p < cnt; p += 256){
    int2 sd2 = pairs[base + p];
    int pos = atomicAdd(&cur[sd2.y & 255], 1);
    srcs[base + pos] = sd2.x;
  }
  if (b == 0 && t == 0) offs[N] = E2;
}

// ---------------- node-parallel softmax-aggregation (software-pipelined, unroll 8) ----------------
__global__ __launch_bounds__(256) void agg_l1(const float* __restrict__ h1, const float* __restrict__ asrc,
                       const float* __restrict__ adst, const int* __restrict__ offs,
                       const int* __restrict__ srcs, const float* __restrict__ bias,
                       short* __restrict__ hout, int N){
  int tid = threadIdx.x;
  int i = blockIdx.x*4 + (tid >> 6);
  int lane = tid & 63;
  if (i >= N) return;
  int hgrp = lane >> 3;
  float ad = adst[i*8 + hgrp];
  int beg = offs[i], end = offs[i + 1];
  float acc = 0.f, den = 0.f;
  int p = beg;
  for (; p + 8 <= end; p += 8){
    int s[8];
#pragma unroll
    for (int u = 0; u < 8; ++u) s[u] = srcs[p + u];
    float az[8];
#pragma unroll
    for (int u = 0; u < 8; ++u) az[u] = asrc[s[u]*8 + hgrp];
    float v[8];
#pragma unroll
    for (int u = 0; u < 8; ++u) v[u] = h1[(size_t)s[u]*64 + lane];
#pragma unroll
    for (int u = 0; u < 8; ++u){
      float z = az[u] + ad;
      z = (z >= 0.f) ? z : NEG_SLOPE*z;
      float e = __expf(z);
      den += e;
      acc = fmaf(e, v[u], acc);
    }
  }
  for (; p < end; ++p){
    int s = srcs[p];
    float z = asrc[s*8 + hgrp] + ad;
    z = (z >= 0.f) ? z : NEG_SLOPE*z;
    float e = __expf(z);
    den += e;
    acc = fmaf(e, h1[(size_t)s*64 + lane], acc);
  }
  float o = acc/(den + EPSV) + bias[lane];
  o = (o > 0.f) ? o : (__expf(o) - 1.f);   // ELU fused
  hout[(size_t)i*64 + lane] = bf16r(o);
}

__global__ __launch_bounds__(256) void agg_l2(const float* __restrict__ h2, const float* __restrict__ asrc,
                       const float* __restrict__ adst, const int* __restrict__ offs,
                       const int* __restrict__ srcs, const float* __restrict__ bias,
                       float* __restrict__ out, int N){
  int tid = threadIdx.x;
  int i = blockIdx.x*4 + (tid >> 6);
  int lane = tid & 63;
  if (i >= N) return;
  float ad = adst[i];
  int beg = offs[i], end = offs[i + 1];
  float a0 = 0.f, a1 = 0.f, den = 0.f;
  int p = beg;
  for (; p + 8 <= end; p += 8){
    int s[8];
#pragma unroll
    for (int u = 0; u < 8; ++u) s[u] = srcs[p + u];
    float az[8];
#pragma unroll
    for (int u = 0; u < 8; ++u) az[u] = asrc[s[u]];
    float v0[8], v1[8];
#pragma unroll
    for (int u = 0; u < 8; ++u){
      v0[u] = h2[(size_t)s[u]*128 + lane];
      v1[u] = h2[(size_t)s[u]*128 + 64 + lane];
    }
#pragma unroll
    for (int u = 0; u < 8; ++u){
      float z = az[u] + ad;
      z = (z >= 0.f) ? z : NEG_SLOPE*z;
      float e = __expf(z);
      den += e;
      a0 = fmaf(e, v0[u], a0);
      a1 = fmaf(e, v1[u], a1);
    }
  }
  for (; p < end; ++p){
    int s = srcs[p];
    float z = asrc[s] + ad;
    z = (z >= 0.f) ? z : NEG_SLOPE*z;
    float e = __expf(z);
    den += e;
    a0 = fmaf(e, h2[(size_t)s*128 + lane], a0);
    a1 = fmaf(e, h2[(size_t)s*128 + 64 + lane], a1);
  }
  float inv = 1.f/(den + EPSV);
  out[(size_t)i*128 + lane]      = a0*inv + bias[lane];
  out[(size_t)i*128 + 64 + lane] = a1*inv + bias[64 + lane];
}

// ---------------- launch ----------------
extern "C" void kernel_launch(void* const* d_in, const int* in_sizes, int n_in,
                              void* d_out, int out_size, void* d_ws, size_t ws_size,
                              hipStream_t stream){
  const float* x   = (const float*)d_in[0];
  const void*  ei  = d_in[1];
  const float* W1  = (const float*)d_in[2];
  const float* as1 = (const float*)d_in[3];
  const float* ad1 = (const float*)d_in[4];
  const float* b1  = (const float*)d_in[5];
  const float* W2  = (const float*)d_in[6];
  const float* as2 = (const float*)d_in[7];
  const float* ad2 = (const float*)d_in[8];
  const float* b2  = (const float*)d_in[9];

  int N  = in_sizes[0] / 128;
  int E  = in_sizes[1] / 2;
  int E2 = E + N;
  int NB = (N + 255) >> 8;   // dst buckets of 256 nodes

  char* p = (char*)d_ws;
  auto alloc = [&](size_t bytes) -> void* {
    void* r = (void*)p;
    p += (bytes + 255) & ~(size_t)255;
    return r;
  };
  short* xb     = (short*)alloc((size_t)N*128*2);
  short* W1p    = (short*)alloc((size_t)128*64*2);
  short* W2p    = (short*)alloc((size_t)64*128*2);
  float* h1     = (float*)alloc((size_t)N*64*4);
  float* asrc1  = (float*)alloc((size_t)N*8*4);
  float* adst1  = (float*)alloc((size_t)N*8*4);
  short* hin2   = (short*)alloc((size_t)N*64*2);
  float* h2     = (float*)alloc((size_t)N*128*4);   // pairs alias this region pre-gemm2
  float* asrc2  = (float*)alloc((size_t)N*4);
  float* adst2  = (float*)alloc((size_t)N*4);
  int*   offs   = (int*)alloc((size_t)(N + 1)*4);
  int*   srcs   = (int*)alloc((size_t)E2*4);
  int*   bcnt   = (int*)alloc((size_t)NBLK*256*4);
  int*   boff   = (int*)alloc((size_t)NBLK*256*4);
  int*   bbase  = (int*)alloc(257*4);
  int*   flag   = (int*)alloc(4);
  int2*  pairs  = (int2*)h2;   // E2*8 bytes <= N*128*4 bytes (13.2 MB <= 25.6 MB)

  dim3 B(256);
  detect_dtype<<<1, 64, 0, stream>>>((const int*)ei, flag);

  int n4 = N*128/4;
  cvt_to_bf16<<<(n4 + 255)/256, B, 0, stream>>>(x, xb, n4);
  pack_w<<<(128*64 + 255)/256, B, 0, stream>>>(W1, W1p, 128, 64);
  pack_w<<<(64*128 + 255)/256, B, 0, stream>>>(W2, W2p, 64, 128);

  int nwav = (N + 15)/16;
  gemm_mfma<128,64><<<(nwav + 3)/4, B, 0, stream>>>(xb, W1p, h1, N);
  logits_l1<<<(N + 3)/4, B, 0, stream>>>(h1, as1, ad1, asrc1, adst1, N);

  // CSR by dst via two-level counting sort (reused by both layers)
  p1_hist<<<NBLK, B, 0, stream>>>(ei, flag, E, E2, bcnt);
  p2_bucket_scan<<<1, B, 0, stream>>>(bcnt, bbase);
  p2_block_off<<<256, B, 0, stream>>>(bcnt, bbase, boff);
  p3_scatter<<<NBLK, B, 0, stream>>>(ei, flag, E, E2, boff, pairs);
  p4_sort<<<NB, B, 0, stream>>>(pairs, bbase, N, E2, offs, srcs);

  agg_l1<<<(N + 3)/4, B, 0, stream>>>(h1, asrc1, adst1, offs, srcs, b1, hin2, N);

  gemm_mfma<64,128><<<(nwav + 3)/4, B, 0, stream>>>(hin2, W2p, h2, N);
  logits_l2<<<(N + 3)/4, B, 0, stream>>>(h2, as2, ad2, asrc2, adst2, N);
  agg_l2<<<(N + 3)/4, B, 0, stream>>>(h2, asrc2, adst2, offs, srcs, b2, (float*)d_out, N);
}

// Round 4
// 318.298 us; speedup vs baseline: 2.1363x; 1.1441x over previous
//
#include <hip/hip_runtime.h>
#include <stdint.h>

#define NEG_SLOPE 0.2f
#define EPSV 1e-16f
#define NBLK 256   // scatter/histogram blocks (fixed, deterministic edge ranges)

typedef __attribute__((ext_vector_type(8))) short short8;
typedef __attribute__((ext_vector_type(4))) float f32x4;

// round-to-nearest-even fp32 -> bf16 bits
__device__ inline short bf16r(float f){
  union { float f; unsigned u; } v; v.f = f;
  unsigned r = (v.u + 0x7FFFu + ((v.u >> 16) & 1u)) >> 16;
  return (short)r;
}
__device__ inline float bf16lo(unsigned u){  // low bf16 of a packed pair
  union { unsigned u; float f; } v; v.u = u << 16; return v.f;
}
__device__ inline float bf16hi(unsigned u){  // high bf16 of a packed pair
  union { unsigned u; float f; } v; v.u = u & 0xFFFF0000u; return v.f;
}

// ---------------- edge access (int32 or int64 edge_index, [2,E] row-major) ----------------
__device__ inline void get_edge(const void* ei, int is64, int E, int e, int& s, int& d){
  if (e >= E){ s = d = e - E; return; }  // self loops appended
  if (is64){
    const long long* p = (const long long*)ei;
    s = (int)p[e]; d = (int)p[(long long)E + e];
  } else {
    const int* p = (const int*)ei;
    s = p[e]; d = p[E + e];
  }
}

__device__ inline int get_dst(const void* ei, int is64, int E, int e){
  if (e >= E) return e - E;
  if (is64) return (int)((const long long*)ei)[(long long)E + e];
  return ((const int*)ei)[E + e];
}

__global__ void detect_dtype(const int* ei32, int* flag){
  if (threadIdx.x == 0 && blockIdx.x == 0){
    int nz = 0;
    for (int i = 0; i < 64; ++i) nz |= ei32[2*i + 1];  // int64: high words all 0
    *flag = (nz == 0) ? 1 : 0;
  }
}

// ---------------- fp32 -> bf16 conversion (vectorized: 4 elems/thread) ----------------
__global__ void cvt_to_bf16(const float* __restrict__ x, short* __restrict__ xb, int n4){
  int i = blockIdx.x*blockDim.x + threadIdx.x;
  if (i >= n4) return;
  f32x4 v = *(const f32x4*)(x + (size_t)i*4);
  short4 o;
  o.x = bf16r(v[0]); o.y = bf16r(v[1]); o.z = bf16r(v[2]); o.w = bf16r(v[3]);
  *(short4*)(xb + (size_t)i*4) = o;
}

// ---------------- pack W [K x NCOL] row-major fp32 -> per-fragment bf16 layout ----------------
__global__ void pack_w(const float* __restrict__ W, short* __restrict__ Wp, int K, int NCOL){
  int NNT = NCOL >> 4;
  int total = K*NCOL;
  int idx = blockIdx.x*blockDim.x + threadIdx.x;
  if (idx >= total) return;
  int j = idx & 7, n16 = (idx >> 3) & 15, q = (idx >> 7) & 3, tile = idx >> 9;
  int nt = tile % NNT, kt = tile / NNT;
  int k = kt*32 + q*8 + j, n = nt*16 + n16;
  Wp[idx] = bf16r(W[k*NCOL + n]);
}

// ---------------- MFMA GEMM: C (fp32) and Cb (bf16 copy) ----------------
template<int K, int NCOL>
__global__ __launch_bounds__(256) void gemm_mfma(const short* __restrict__ A, const short* __restrict__ Bp,
                                                 float* __restrict__ C, short* __restrict__ Cb, int M){
  constexpr int NKT = K/32, NNT = NCOL/16;
  int wave = (blockIdx.x*256 + (int)threadIdx.x) >> 6;
  int lane = threadIdx.x & 63;
  int row0 = wave << 4;
  if (row0 >= M) return;
  int m = lane & 15, q = lane >> 4;
  f32x4 acc[NNT];
#pragma unroll
  for (int i = 0; i < NNT; ++i) acc[i] = (f32x4){0.f,0.f,0.f,0.f};
#pragma unroll
  for (int kt = 0; kt < NKT; ++kt){
    short8 a = *(const short8*)(A + (size_t)(row0 + m)*K + kt*32 + q*8);
#pragma unroll
    for (int nt = 0; nt < NNT; ++nt){
      short8 b = *(const short8*)(Bp + (size_t)(((kt*NNT + nt)*4 + q)*16 + m)*8);
      acc[nt] = __builtin_amdgcn_mfma_f32_16x16x32_bf16(a, b, acc[nt], 0, 0, 0);
    }
  }
#pragma unroll
  for (int nt = 0; nt < NNT; ++nt){
#pragma unroll
    for (int r = 0; r < 4; ++r){
      float v = acc[nt][r];
      size_t idx = (size_t)(row0 + q*4 + r)*NCOL + nt*16 + m;
      C[idx] = v;
      Cb[idx] = bf16r(v);
    }
  }
}

// ---------------- attention logit reductions ----------------
__global__ void logits_l1(const float* __restrict__ h1, const float* __restrict__ att_s,
                          const float* __restrict__ att_d, float* __restrict__ asrc,
                          float* __restrict__ adst, int N){
  int tid = threadIdx.x;
  int n = blockIdx.x*4 + (tid >> 6);
  int j = tid & 63;
  if (n >= N) return;
  float h = h1[(size_t)n*64 + j];
  float ps = h * att_s[j];
  float pd = h * att_d[j];
#pragma unroll
  for (int mm = 4; mm; mm >>= 1){ ps += __shfl_xor(ps, mm, 8); pd += __shfl_xor(pd, mm, 8); }
  if ((j & 7) == 0){ asrc[n*8 + (j >> 3)] = ps; adst[n*8 + (j >> 3)] = pd; }
}

__global__ void logits_l2(const float* __restrict__ h2, const float* __restrict__ att_s,
                          const float* __restrict__ att_d, float* __restrict__ asrc,
                          float* __restrict__ adst, int N){
  int tid = threadIdx.x;
  int n = blockIdx.x*4 + (tid >> 6);
  int l = tid & 63;
  if (n >= N) return;
  float a = h2[(size_t)n*128 + l], b = h2[(size_t)n*128 + 64 + l];
  float ps = a*att_s[l] + b*att_s[64 + l];
  float pd = a*att_d[l] + b*att_d[64 + l];
#pragma unroll
  for (int mm = 32; mm; mm >>= 1){ ps += __shfl_xor(ps, mm, 64); pd += __shfl_xor(pd, mm, 64); }
  if (l == 0){ asrc[n] = ps; adst[n] = pd; }
}

// ================= CSR build: two-level counting sort (no global atomics) =================
__global__ __launch_bounds__(256) void p1_hist(const void* ei, const int* flag, int E, int E2,
                                               int* __restrict__ block_counts){
  __shared__ int h[256];
  int t = threadIdx.x, blk = blockIdx.x;
  h[t] = 0; __syncthreads();
  int chunk = (E2 + NBLK - 1)/NBLK;
  int beg = blk*chunk, end = min(beg + chunk, E2);
  int is64 = *flag;
  for (int e = beg + t; e < end; e += 256){
    int d = get_dst(ei, is64, E, e);
    atomicAdd(&h[d >> 8], 1);
  }
  __syncthreads();
  block_counts[blk*256 + t] = h[t];
}

__global__ void p2_bucket_scan(const int* __restrict__ block_counts, int* __restrict__ bucket_base){
  __shared__ int sd[256];
  int t = threadIdx.x;
  int tot = 0;
  for (int b = 0; b < NBLK; ++b) tot += block_counts[b*256 + t];
  sd[t] = tot; __syncthreads();
  for (int off = 1; off < 256; off <<= 1){
    int v = (t >= off) ? sd[t - off] : 0;
    __syncthreads(); sd[t] += v; __syncthreads();
  }
  bucket_base[t] = sd[t] - tot;            // exclusive
  if (t == 255) bucket_base[256] = sd[255];
}

__global__ void p2_block_off(const int* __restrict__ block_counts, const int* __restrict__ bucket_base,
                             int* __restrict__ block_off){
  __shared__ int sd[256];
  int b = blockIdx.x, t = threadIdx.x;
  int v = block_counts[t*256 + b];
  sd[t] = v; __syncthreads();
  for (int off = 1; off < 256; off <<= 1){
    int u = (t >= off) ? sd[t - off] : 0;
    __syncthreads(); sd[t] += u; __syncthreads();
  }
  block_off[t*256 + b] = bucket_base[b] + sd[t] - v;
}

__global__ __launch_bounds__(256) void p3_scatter(const void* ei, const int* flag, int E, int E2,
                                                  const int* __restrict__ block_off,
                                                  int2* __restrict__ pairs){
  __shared__ int cur[256];
  int t = threadIdx.x, blk = blockIdx.x;
  cur[t] = block_off[blk*256 + t];
  __syncthreads();
  int chunk = (E2 + NBLK - 1)/NBLK;
  int beg = blk*chunk, end = min(beg + chunk, E2);
  int is64 = *flag;
  for (int e = beg + t; e < end; e += 256){
    int s, d; get_edge(ei, is64, E, e, s, d);
    int pos = atomicAdd(&cur[d >> 8], 1);
    pairs[pos] = make_int2(s, d);
  }
}

__global__ __launch_bounds__(256) void p4_sort(const int2* __restrict__ pairs,
                                               const int* __restrict__ bucket_base,
                                               int N, int E2,
                                               int* __restrict__ offs, int* __restrict__ srcs){
  __shared__ int hist[256];
  __shared__ int cur[256];
  int b = blockIdx.x, t = threadIdx.x;
  int base = bucket_base[b], cnt = bucket_base[b + 1] - base;
  hist[t] = 0; __syncthreads();
  for (int p = t; p < cnt; p += 256){
    int2 sd2 = pairs[base + p];
    atomicAdd(&hist[sd2.y & 255], 1);
  }
  __syncthreads();
  int v = hist[t];
  cur[t] = v; __syncthreads();
  for (int off = 1; off < 256; off <<= 1){
    int u = (t >= off) ? cur[t - off] : 0;
    __syncthreads(); cur[t] += u; __syncthreads();
  }
  int ex = cur[t] - v;   // exclusive prefix within bucket
  __syncthreads();
  cur[t] = ex;
  int node = b*256 + t;
  if (node < N) offs[node] = base + ex;
  __syncthreads();
  for (int p = t; p < cnt; p += 256){
    int2 sd2 = pairs[base + p];
    int pos = atomicAdd(&cur[sd2.y & 255], 1);
    srcs[base + pos] = sd2.x;
  }
  if (b == 0 && t == 0) offs[N] = E2;
}

// ---------------- node-parallel softmax-aggregation (bf16 gathers, unroll 8) ----------------
__global__ __launch_bounds__(256) void agg_l1(const unsigned short* __restrict__ h1b,
                       const float* __restrict__ asrc,
                       const float* __restrict__ adst, const int* __restrict__ offs,
                       const int* __restrict__ srcs, const float* __restrict__ bias,
                       short* __restrict__ hout, int N){
  int tid = threadIdx.x;
  int i = blockIdx.x*4 + (tid >> 6);
  int lane = tid & 63;
  if (i >= N) return;
  int hgrp = lane >> 3;
  float ad = adst[i*8 + hgrp];
  int beg = offs[i], end = offs[i + 1];
  float acc = 0.f, den = 0.f;
  int p = beg;
  for (; p + 8 <= end; p += 8){
    int s[8];
#pragma unroll
    for (int u = 0; u < 8; ++u) s[u] = srcs[p + u];
    float az[8];
#pragma unroll
    for (int u = 0; u < 8; ++u) az[u] = asrc[s[u]*8 + hgrp];
    unsigned v[8];
#pragma unroll
    for (int u = 0; u < 8; ++u) v[u] = h1b[(size_t)s[u]*64 + lane];
#pragma unroll
    for (int u = 0; u < 8; ++u){
      float z = az[u] + ad;
      z = (z >= 0.f) ? z : NEG_SLOPE*z;
      float e = __expf(z);
      den += e;
      acc = fmaf(e, bf16lo(v[u]), acc);
    }
  }
  for (; p < end; ++p){
    int s = srcs[p];
    float z = asrc[s*8 + hgrp] + ad;
    z = (z >= 0.f) ? z : NEG_SLOPE*z;
    float e = __expf(z);
    den += e;
    acc = fmaf(e, bf16lo((unsigned)h1b[(size_t)s*64 + lane]), acc);
  }
  float o = acc/(den + EPSV) + bias[lane];
  o = (o > 0.f) ? o : (__expf(o) - 1.f);   // ELU fused
  hout[(size_t)i*64 + lane] = bf16r(o);
}

// lane owns cols {2*lane, 2*lane+1}; one uint (2 bf16) load per edge
__global__ __launch_bounds__(256) void agg_l2(const unsigned* __restrict__ h2b2,
                       const float* __restrict__ asrc,
                       const float* __restrict__ adst, const int* __restrict__ offs,
                       const int* __restrict__ srcs, const float* __restrict__ bias,
                       float* __restrict__ out, int N){
  int tid = threadIdx.x;
  int i = blockIdx.x*4 + (tid >> 6);
  int lane = tid & 63;
  if (i >= N) return;
  float ad = adst[i];
  int beg = offs[i], end = offs[i + 1];
  float a0 = 0.f, a1 = 0.f, den = 0.f;
  int p = beg;
  for (; p + 8 <= end; p += 8){
    int s[8];
#pragma unroll
    for (int u = 0; u < 8; ++u) s[u] = srcs[p + u];
    float az[8];
#pragma unroll
    for (int u = 0; u < 8; ++u) az[u] = asrc[s[u]];
    unsigned v[8];
#pragma unroll
    for (int u = 0; u < 8; ++u) v[u] = h2b2[(size_t)s[u]*64 + lane];
#pragma unroll
    for (int u = 0; u < 8; ++u){
      float z = az[u] + ad;
      z = (z >= 0.f) ? z : NEG_SLOPE*z;
      float e = __expf(z);
      den += e;
      a0 = fmaf(e, bf16lo(v[u]), a0);
      a1 = fmaf(e, bf16hi(v[u]), a1);
    }
  }
  for (; p < end; ++p){
    int s = srcs[p];
    float z = asrc[s] + ad;
    z = (z >= 0.f) ? z : NEG_SLOPE*z;
    float e = __expf(z);
    den += e;
    unsigned v = h2b2[(size_t)s*64 + lane];
    a0 = fmaf(e, bf16lo(v), a0);
    a1 = fmaf(e, bf16hi(v), a1);
  }
  float inv = 1.f/(den + EPSV);
  int c0 = lane*2;
  float2 o;
  o.x = a0*inv + bias[c0];
  o.y = a1*inv + bias[c0 + 1];
  *(float2*)(out + (size_t)i*128 + c0) = o;
}

// ---------------- launch ----------------
extern "C" void kernel_launch(void* const* d_in, const int* in_sizes, int n_in,
                              void* d_out, int out_size, void* d_ws, size_t ws_size,
                              hipStream_t stream){
  const float* x   = (const float*)d_in[0];
  const void*  ei  = d_in[1];
  const float* W1  = (const float*)d_in[2];
  const float* as1 = (const float*)d_in[3];
  const float* ad1 = (const float*)d_in[4];
  const float* b1  = (const float*)d_in[5];
  const float* W2  = (const float*)d_in[6];
  const float* as2 = (const float*)d_in[7];
  const float* ad2 = (const float*)d_in[8];
  const float* b2  = (const float*)d_in[9];

  int N  = in_sizes[0] / 128;
  int E  = in_sizes[1] / 2;
  int E2 = E + N;
  int NB = (N + 255) >> 8;   // dst buckets of 256 nodes

  char* p = (char*)d_ws;
  auto alloc = [&](size_t bytes) -> void* {
    void* r = (void*)p;
    p += (bytes + 255) & ~(size_t)255;
    return r;
  };
  short* xb     = (short*)alloc((size_t)N*128*2);
  short* W1p    = (short*)alloc((size_t)128*64*2);
  short* W2p    = (short*)alloc((size_t)64*128*2);
  float* h1     = (float*)alloc((size_t)N*64*4);
  short* h1b    = (short*)alloc((size_t)N*64*2);
  float* asrc1  = (float*)alloc((size_t)N*8*4);
  float* adst1  = (float*)alloc((size_t)N*8*4);
  short* hin2   = (short*)alloc((size_t)N*64*2);
  float* h2     = (float*)alloc((size_t)N*128*4);   // pairs alias this region pre-gemm2
  short* h2b    = (short*)alloc((size_t)N*128*2);
  float* asrc2  = (float*)alloc((size_t)N*4);
  float* adst2  = (float*)alloc((size_t)N*4);
  int*   offs   = (int*)alloc((size_t)(N + 1)*4);
  int*   srcs   = (int*)alloc((size_t)E2*4);
  int*   bcnt   = (int*)alloc((size_t)NBLK*256*4);
  int*   boff   = (int*)alloc((size_t)NBLK*256*4);
  int*   bbase  = (int*)alloc(257*4);
  int*   flag   = (int*)alloc(4);
  int2*  pairs  = (int2*)h2;   // E2*8 bytes <= N*128*4 bytes (13.2 MB <= 25.6 MB)

  dim3 B(256);
  detect_dtype<<<1, 64, 0, stream>>>((const int*)ei, flag);

  int n4 = N*128/4;
  cvt_to_bf16<<<(n4 + 255)/256, B, 0, stream>>>(x, xb, n4);
  pack_w<<<(128*64 + 255)/256, B, 0, stream>>>(W1, W1p, 128, 64);
  pack_w<<<(64*128 + 255)/256, B, 0, stream>>>(W2, W2p, 64, 128);

  int nwav = (N + 15)/16;
  gemm_mfma<128,64><<<(nwav + 3)/4, B, 0, stream>>>(xb, W1p, h1, h1b, N);
  logits_l1<<<(N + 3)/4, B, 0, stream>>>(h1, as1, ad1, asrc1, adst1, N);

  // CSR by dst via two-level counting sort (reused by both layers)
  p1_hist<<<NBLK, B, 0, stream>>>(ei, flag, E, E2, bcnt);
  p2_bucket_scan<<<1, B, 0, stream>>>(bcnt, bbase);
  p2_block_off<<<256, B, 0, stream>>>(bcnt, bbase, boff);
  p3_scatter<<<NBLK, B, 0, stream>>>(ei, flag, E, E2, boff, pairs);
  p4_sort<<<NB, B, 0, stream>>>(pairs, bbase, N, E2, offs, srcs);

  agg_l1<<<(N + 3)/4, B, 0, stream>>>((const unsigned short*)h1b, asrc1, adst1, offs, srcs, b1, hin2, N);

  gemm_mfma<64,128><<<(nwav + 3)/4, B, 0, stream>>>(hin2, W2p, h2, h2b, N);
  logits_l2<<<(N + 3)/4, B, 0, stream>>>(h2, as2, ad2, asrc2, adst2, N);
  agg_l2<<<(N + 3)/4, B, 0, stream>>>((const unsigned*)h2b, asrc2, adst2, offs, srcs, b2, (float*)d_out, N);
}